// Round 3
// baseline (17498.810 us; speedup 1.0000x reference)
//
#include <hip/hip_runtime.h>
#include <hip/hip_bf16.h>
#include <math.h>

#define EPSF 1e-7f
#define MAXNRM 0.99999f

static constexpr int Bb = 16, Ss = 128, Hh = 512, Vv = 10000, Ll = 3;
static constexpr int Nn = Bb * Ss; // 2048
static constexpr int NBLK = 16;    // scan blocks (hidden-dim split)

typedef __attribute__((ext_vector_type(8))) short short8v;
typedef __attribute__((ext_vector_type(4))) float f32x4;

__device__ inline float4 ld4(const float* p){ return *(const float4*)p; }
__device__ inline void st4(float* p, float4 v){ *(float4*)p = v; }
__device__ inline float dot4(float4 a, float4 b){ return a.x*b.x + a.y*b.y + a.z*b.z + a.w*b.w; }
__device__ inline float sigm(float x){ return 1.f/(1.f + expf(-x)); }
__device__ inline unsigned short f2bf(float f){
  __hip_bfloat16 h = __float2bfloat16(f);
  return __builtin_bit_cast(unsigned short, h);
}
__device__ inline float rsum64f(float v){
  v+=__shfl_xor(v,32); v+=__shfl_xor(v,16); v+=__shfl_xor(v,8);
  v+=__shfl_xor(v,4);  v+=__shfl_xor(v,2);  v+=__shfl_xor(v,1); return v;
}
__device__ inline float rsum32f(float v){
  v+=__shfl_xor(v,16); v+=__shfl_xor(v,8); v+=__shfl_xor(v,4);
  v+=__shfl_xor(v,2);  v+=__shfl_xor(v,1); return v;
}
__device__ inline float rsum16f(float v){
  v+=__shfl_xor(v,8); v+=__shfl_xor(v,4); v+=__shfl_xor(v,2); v+=__shfl_xor(v,1); return v;
}

// ---------------- pack W[l][j][k] -> bf16 MFMA B-fragments per scan-block ----------------
// layout: Wp[l][g][mat][kt 16][nt 2][lane 64][8]  (elem: W[j=g*32+nt*16+(lane&15)][k=kt*32+(lane>>4)*8+i])
__global__ void k_pack(const float* __restrict__ Wr, const float* __restrict__ Wz,
                       const float* __restrict__ Wh, ushort* __restrict__ Wp){
  int g = blockIdx.x, lm = blockIdx.y;
  int l = lm/3, mat = lm%3;
  const float* W = (mat==0?Wr:mat==1?Wz:Wh) + (size_t)l*Hh*Hh;
  int tid = threadIdx.x;
  int kt = tid>>6, lane = tid&63, q = (lane>>4)&3, nl = lane&15;
  #pragma unroll
  for(int nt=0;nt<2;nt++){
    int j = g*32 + nt*16 + nl;
    int k0 = kt*32 + q*8;
    const float* src = W + (size_t)j*Hh + k0;
    union { ushort u[8]; uint4 v; } tmp;
    #pragma unroll
    for(int i=0;i<8;i++) tmp.u[i] = f2bf(src[i]);
    size_t off = ((((((size_t)l*NBLK + g)*3 + mat)*16 + kt)*2 + nt)*64 + lane)*8;
    *(uint4*)(Wp + off) = tmp.v;
  }
}

// ---------------- per-(t,b) input-only dots ----------------
// pubX[n][6] = {xr.xr, xr.br, xz.xz, xz.bz, xh.xh, xh.bh}
__global__ void k_predots(const float* __restrict__ XR, const float* __restrict__ XZ,
                          const float* __restrict__ XH,
                          const float* __restrict__ br, const float* __restrict__ bz,
                          const float* __restrict__ bh, float* __restrict__ pubX){
  int n = blockIdx.x; int tid = threadIdx.x; // 128 threads
  float s0=0,s1=0,s2=0,s3=0,s4=0,s5=0;
  for(int i=tid;i<Hh;i+=128){
    float xr=XR[(size_t)n*Hh+i], xz=XZ[(size_t)n*Hh+i], xh=XH[(size_t)n*Hh+i];
    s0+=xr*xr; s1+=xr*br[i]; s2+=xz*xz; s3+=xz*bz[i]; s4+=xh*xh; s5+=xh*bh[i];
  }
  __shared__ float red[2][6];
  s0=rsum64f(s0); s1=rsum64f(s1); s2=rsum64f(s2);
  s3=rsum64f(s3); s4=rsum64f(s4); s5=rsum64f(s5);
  int w = tid>>6;
  if((tid&63)==0){ red[w][0]=s0; red[w][1]=s1; red[w][2]=s2; red[w][3]=s3; red[w][4]=s4; red[w][5]=s5; }
  __syncthreads();
  if(tid==0){
    #pragma unroll
    for(int d=0;d<6;d++) pubX[(size_t)n*6+d] = red[0][d]+red[1][d];
  }
}

// ---------------- per-vocab constants ----------------
__global__ void k_pav(const float* __restrict__ P, const float* __restrict__ A,
                      float* __restrict__ pp, float* __restrict__ aa, float* __restrict__ pa){
  int w = threadIdx.x >> 6, lane = threadIdx.x & 63;
  int v = blockIdx.x*4 + w;
  const float4* Pr = (const float4*)(P + (size_t)v*Hh);
  const float4* Ar = (const float4*)(A + (size_t)v*Hh);
  float sp=0, sa=0, spa=0;
  #pragma unroll
  for(int i=0;i<2;i++){
    int k4 = lane*2 + i;
    float4 pv = Pr[k4], av = Ar[k4];
    sp += dot4(pv,pv); sa += dot4(av,av); spa += dot4(pv,av);
  }
  for(int o=32;o;o>>=1){ sp+=__shfl_down(sp,o); sa+=__shfl_down(sa,o); spa+=__shfl_down(spa,o); }
  if(lane==0){ pp[v]=sp; aa[v]=sqrtf(sa+EPSF); pa[v]=spa; }
}

// ---------------- embedding gather ----------------
__global__ void k_embed(const int* __restrict__ inp, const float* __restrict__ E, float* __restrict__ X){
  int n = blockIdx.x; int t = n >> 4, b = n & 15;
  int tok = inp[b*Ss + t];
  int i = threadIdx.x;
  st4(X + (size_t)n*Hh + i*4, ld4(E + (size_t)tok*Hh + i*4));
}

// ---------------- row logmap0 ----------------
__global__ void k_logmap(const float* __restrict__ X, float* __restrict__ LX){
  int n = blockIdx.x; int t = threadIdx.x;
  __shared__ float sred[2];
  float4 v = ld4(X + (size_t)n*Hh + t*4);
  float ss = dot4(v,v);
  for(int o=32;o;o>>=1) ss += __shfl_down(ss,o);
  if((t&63)==0) sred[t>>6] = ss;
  __syncthreads();
  ss = sred[0]+sred[1];
  float nn = sqrtf(ss + EPSF);
  float sc = atanhf(fminf(nn, MAXNRM)) / nn;
  v.x*=sc; v.y*=sc; v.z*=sc; v.w*=sc;
  st4(LX + (size_t)n*Hh + t*4, v);
}

// ---------------- row expmap0 (in place, 3 buffers) ----------------
__global__ void k_expmap(float* __restrict__ XR, float* __restrict__ XZ, float* __restrict__ XH){
  float* Xp = blockIdx.y==0 ? XR : (blockIdx.y==1 ? XZ : XH);
  int n = blockIdx.x; int t = threadIdx.x;
  __shared__ float sred[2];
  float4 v = ld4(Xp + (size_t)n*Hh + t*4);
  float ss = dot4(v,v);
  for(int o=32;o;o>>=1) ss += __shfl_down(ss,o);
  if((t&63)==0) sred[t>>6] = ss;
  __syncthreads();
  ss = sred[0]+sred[1];
  float nn = sqrtf(ss + EPSF);
  float sc = tanhf(nn) / nn;
  v.x*=sc; v.y*=sc; v.z*=sc; v.w*=sc;
  st4(Xp + (size_t)n*Hh + t*4, v);
}

// ---------------- GEMM: LX[2048,512] @ {Ur|Uz|Uh}^T ----------------
__global__ __launch_bounds__(256) void k_gemm(const float* __restrict__ A4,
    const float* __restrict__ U0, const float* __restrict__ U1, const float* __restrict__ U2,
    float* __restrict__ O0, float* __restrict__ O1, float* __restrict__ O2){
  __shared__ float As[16][65], Bs[16][65];
  int jb = blockIdx.x;
  int nb = blockIdx.y;
  int mat = jb >> 3; int j0 = (jb & 7)*64;
  const float* Bm = mat==0?U0 : (mat==1?U1:U2);
  float* Om       = mat==0?O0 : (mat==1?O1:O2);
  int tid = threadIdx.x;
  int lr = tid >> 2, lq = tid & 3;
  int tx = tid & 15, ty = tid >> 4;
  float acc[4][4] = {};
  for(int kb=0; kb<Hh; kb+=16){
    float4 av = ld4(A4 + (size_t)(nb*64+lr)*Hh + kb + lq*4);
    float4 bv = ld4(Bm + (size_t)(j0+lr)*Hh + kb + lq*4);
    As[lq*4+0][lr]=av.x; As[lq*4+1][lr]=av.y; As[lq*4+2][lr]=av.z; As[lq*4+3][lr]=av.w;
    Bs[lq*4+0][lr]=bv.x; Bs[lq*4+1][lr]=bv.y; Bs[lq*4+2][lr]=bv.z; Bs[lq*4+3][lr]=bv.w;
    __syncthreads();
    #pragma unroll
    for(int kk=0;kk<16;kk++){
      float a0=As[kk][ty*4+0], a1=As[kk][ty*4+1], a2=As[kk][ty*4+2], a3=As[kk][ty*4+3];
      float b0=Bs[kk][tx*4+0], b1=Bs[kk][tx*4+1], b2=Bs[kk][tx*4+2], b3=Bs[kk][tx*4+3];
      acc[0][0]+=a0*b0; acc[0][1]+=a0*b1; acc[0][2]+=a0*b2; acc[0][3]+=a0*b3;
      acc[1][0]+=a1*b0; acc[1][1]+=a1*b1; acc[1][2]+=a1*b2; acc[1][3]+=a1*b3;
      acc[2][0]+=a2*b0; acc[2][1]+=a2*b1; acc[2][2]+=a2*b2; acc[2][3]+=a2*b3;
      acc[3][0]+=a3*b0; acc[3][1]+=a3*b1; acc[3][2]+=a3*b2; acc[3][3]+=a3*b3;
    }
    __syncthreads();
  }
  for(int i=0;i<4;i++)
    for(int j2=0;j2<4;j2++)
      Om[(size_t)(nb*64+ty*4+i)*Hh + j0 + tx*4 + j2] = acc[i][j2];
}

// ---------------- the cooperative hidden-split GRU scan ----------------
// 16 blocks x 1024 threads. Block g owns hidden cols [g*32, g*32+32) == k-tile g.
// Weights resident in LDS as MFMA B-fragments. 2 grid syncs per step.
__global__ __launch_bounds__(1024) void k_scan3(
    const float* __restrict__ XR, const float* __restrict__ XZ, const float* __restrict__ XH,
    const ushort* __restrict__ Wp_l,
    const float* __restrict__ br, const float* __restrict__ bz, const float* __restrict__ bh,
    const float* __restrict__ pubX,
    float* __restrict__ pmr, float* __restrict__ pmz, float* __restrict__ pmh,
    float* __restrict__ pA, float* __restrict__ pB,
    int* __restrict__ cnt, float* __restrict__ Xout){
  const int g = blockIdx.x;
  const int tid = threadIdx.x;
  const int lane = tid & 63, wv = tid >> 6;  // 16 waves
  const int q = (lane>>4)&3, nl = lane&15;

  __shared__ ushort Wlds[3*16*2*64*8];   // 96 KB: [mat][kt][nt][lane][8]
  __shared__ ushort afAF[16*64*8];       // 16 KB: A-frag [kt][lane][8] (lh then ap)
  __shared__ float biasL0[Hh], biasL1[Hh], biasL2[Hh]; // 6 KB
  __shared__ float mS0[16][32];          // mr slice (ph3) / mh slice (ph6)
  __shared__ float mzS[16][32];
  __shared__ float hSl[16][32];
  __shared__ float dotsA[16][8];
  __shared__ float dotsB[16][18];
  __shared__ float coefA[16][8];
  __shared__ float coefB[16][8];
  __shared__ float ShT[16];
  __shared__ float bbT[4];

  // ---- startup: weights -> LDS (contiguous 96 KB) ----
  {
    const uint4* srcW = (const uint4*)(Wp_l + (size_t)g*49152);
    uint4* dstW = (uint4*)Wlds;
    #pragma unroll
    for(int i=0;i<6;i++) dstW[i*1024+tid] = srcW[i*1024+tid];
  }
  for(int i=tid;i<Hh;i+=1024){ biasL0[i]=br[i]; biasL1[i]=bz[i]; biasL2[i]=bh[i]; }
  { uint4 z4 = {0,0,0,0}; ((uint4*)afAF)[tid] = z4; }
  if(tid<512) hSl[tid>>5][tid&31] = 0.f;
  if(tid<16) ShT[tid] = 0.f;
  __syncthreads();
  // bias grams
  {
    float p0=0,p1=0,p2=0;
    if(tid<512){ float a=biasL0[tid],b2=biasL1[tid],c2=biasL2[tid]; p0=a*a; p1=b2*b2; p2=c2*c2; }
    p0=rsum64f(p0); p1=rsum64f(p1); p2=rsum64f(p2);
    if(tid<512 && (tid&63)==0){ dotsB[tid>>6][0]=p0; dotsB[tid>>6][1]=p1; dotsB[tid>>6][2]=p2; }
    __syncthreads();
    if(tid==0){
      float a=0,b2=0,c2=0;
      for(int i=0;i<8;i++){ a+=dotsB[i][0]; b2+=dotsB[i][1]; c2+=dotsB[i][2]; }
      bbT[0]=a; bbT[1]=b2; bbT[2]=c2;
    }
    __syncthreads();
  }

  float hreg[8], lhreg[8];
  #pragma unroll
  for(int i=0;i<8;i++){ hreg[i]=0.f; lhreg[i]=0.f; }
  int bcnt = 0;

  auto gsync = [&](){
    __threadfence();
    __syncthreads();
    bcnt += NBLK;
    if(tid==0){
      __hip_atomic_fetch_add(cnt, 1, __ATOMIC_RELEASE, __HIP_MEMORY_SCOPE_AGENT);
      while(__hip_atomic_load(cnt, __ATOMIC_ACQUIRE, __HIP_MEMORY_SCOPE_AGENT) < bcnt){
        __builtin_amdgcn_s_sleep(1);
      }
    }
    __syncthreads();
    __threadfence();
  };

  for(int ts=0; ts<Ss; ts++){
    const size_t rb16 = (size_t)(ts*Bb)*Hh;
    float* pmzW = pmz + (ts&1)*8192;

    // ---- phase 2: matvec r/z via MFMA (waves 0..3) ----
    if(wv < 4){
      int mat = wv>>1, nt = wv&1;
      f32x4 acc = {0.f,0.f,0.f,0.f};
      #pragma unroll
      for(int kt2=0;kt2<16;kt2++){
        short8v av = *(const short8v*)&afAF[((size_t)kt2*64+lane)*8];
        short8v bv = *(const short8v*)&Wlds[((((size_t)mat*16+kt2)*2+nt)*64+lane)*8];
        acc = __builtin_amdgcn_mfma_f32_16x16x32_bf16(av, bv, acc, 0,0,0);
      }
      float* pdst = (mat==0)? pmr : pmzW;
      int colg = g*32 + nt*16 + nl;
      #pragma unroll
      for(int rr=0;rr<4;rr++){
        int brow = q*4+rr;
        pdst[brow*Hh + colg] = acc[rr];
        if(mat==0) mS0[brow][nt*16+nl] = acc[rr];
        else       mzS[brow][nt*16+nl] = acc[rr];
      }
    }
    __syncthreads();

    // ---- phase 3: partial dots over slice ----
    if(tid<512){
      int b2 = tid>>5, c = tid&31, colg = g*32+c;
      size_t rb = rb16 + (size_t)b2*Hh;
      float mr = mS0[b2][c], mz = mzS[b2][c], hv = hSl[b2][c];
      float xr = XR[rb+colg], xz = XZ[rb+colg], xh = XH[rb+colg];
      float brc = biasL0[colg], bzc = biasL1[colg], bhc = biasL2[colg];
      float p[8] = {mr*mr, mr*xr, mr*brc, mz*mz, mz*xz, mz*bzc, hv*xh, hv*bhc};
      #pragma unroll
      for(int d=0;d<8;d++) p[d] = rsum32f(p[d]);
      if(c==0){
        float* dst = pA + ((size_t)g*16+b2)*8;
        #pragma unroll
        for(int d=0;d<8;d++) dst[d]=p[d];
      }
    }
    gsync();  // sync A

    // ---- phase 4a: sum partials ----
    if(tid<256){
      int b2 = tid>>4, blk = tid&15;
      const float* src = pA + ((size_t)blk*16+b2)*8;
      float s[8];
      #pragma unroll
      for(int d=0;d<8;d++) s[d]=src[d];
      #pragma unroll
      for(int d=0;d<8;d++) s[d]=rsum16f(s[d]);
      if(blk==0){
        #pragma unroll
        for(int d=0;d<8;d++) dotsA[b2][d]=s[d];
      }
    }
    __syncthreads();

    // ---- phase 4b: gate coefficients (16 threads, one per batch row) ----
    if(tid<16){
      int b2 = tid;
      float s0=dotsA[b2][0], s1=dotsA[b2][1], s2=dotsA[b2][2];
      float s3=dotsA[b2][3], s4=dotsA[b2][4], s5=dotsA[b2][5];
      const float* px = pubX + (size_t)(ts*Bb+b2)*6;
      float xrxr=px[0], xrbr=px[1], xzxz=px[2], xzbz=px[3];
      float bbr=bbT[0], bbz=bbT[1];
      // r chain
      float nm=sqrtf(s0+EPSF), se=tanhf(nm)/nm;
      float uv=se*s1, uu=se*se*s0, vvr=xrxr;
      float den=1.f+2.f*uv+uu*vvr;
      float a1=(1.f+2.f*uv+vvr)*se/den, a2=(1.f-uu)/den;
      float uv2=a1*s2+a2*xrbr;
      float uu2=a1*a1*s0+2.f*a1*a2*s1+a2*a2*xrxr;
      float den2=1.f+2.f*uv2+uu2*bbr;
      float b1=(1.f+2.f*uv2+bbr)/den2, b2c=(1.f-uu2)/den2;
      float c1=b1*a1, c2=b1*a2, c3=b2c;
      float n2sq=c1*c1*s0+c2*c2*xrxr+c3*c3*bbr+2.f*(c1*c2*s1+c1*c3*s2+c2*c3*xrbr);
      float nn2=sqrtf(n2sq+EPSF);
      float s_r=atanhf(fminf(nn2,MAXNRM))/nn2;
      coefA[b2][0]=s_r*c1; coefA[b2][1]=s_r*c2; coefA[b2][2]=s_r*c3;
      // z chain
      float nmz=sqrtf(s3+EPSF), sez=tanhf(nmz)/nmz;
      float uvz=sez*s4, uuz=sez*sez*s3, vvz=xzxz;
      float denz=1.f+2.f*uvz+uuz*vvz;
      float az1=(1.f+2.f*uvz+vvz)*sez/denz, az2=(1.f-uuz)/denz;
      float uvz2=az1*s5+az2*xzbz;
      float uuz2=az1*az1*s3+2.f*az1*az2*s4+az2*az2*xzxz;
      float denz2=1.f+2.f*uvz2+uuz2*bbz;
      float bz1=(1.f+2.f*uvz2+bbz)/denz2, bz2=(1.f-uuz2)/denz2;
      float cz1=bz1*az1, cz2=bz1*az2, cz3=bz2;
      float nz2sq=cz1*cz1*s3+cz2*cz2*xzxz+cz3*cz3*bbz+2.f*(cz1*cz2*s4+cz1*cz3*s5+cz2*cz3*xzbz);
      float nnz2=sqrtf(nz2sq+EPSF);
      float s_z=atanhf(fminf(nnz2,MAXNRM))/nnz2;
      coefA[b2][3]=s_z*cz1; coefA[b2][4]=s_z*cz2; coefA[b2][5]=s_z*cz3;
    }
    __syncthreads();

    // ---- phase 4c: build ap A-fragment (all threads; slot = (kt=wv, lane)) ----
    {
      int bm = nl;
      int k8 = wv*32 + q*8;
      size_t rb = rb16 + (size_t)bm*Hh;
      f32x4 m0 = *(const f32x4*)(pmr + bm*Hh + k8);
      f32x4 m1 = *(const f32x4*)(pmr + bm*Hh + k8 + 4);
      f32x4 x0 = *(const f32x4*)(XR + rb + k8);
      f32x4 x1 = *(const f32x4*)(XR + rb + k8 + 4);
      float ca=coefA[bm][0], cb=coefA[bm][1], cc=coefA[bm][2];
      short8v o;
      #pragma unroll
      for(int i=0;i<4;i++){
        float rr1 = sigm(ca*m0[i] + cb*x0[i] + cc*biasL0[k8+i]);
        o[i] = (short)f2bf(rr1*lhreg[i]);
      }
      #pragma unroll
      for(int i=0;i<4;i++){
        float rr1 = sigm(ca*m1[i] + cb*x1[i] + cc*biasL0[k8+4+i]);
        o[4+i] = (short)f2bf(rr1*lhreg[4+i]);
      }
      *(short8v*)&afAF[((size_t)wv*64+lane)*8] = o;
    }
    __syncthreads();

    // ---- phase 5: matvec h via MFMA (waves 0..1) ----
    if(wv < 2){
      int nt = wv;
      f32x4 acc = {0.f,0.f,0.f,0.f};
      #pragma unroll
      for(int kt2=0;kt2<16;kt2++){
        short8v av = *(const short8v*)&afAF[((size_t)kt2*64+lane)*8];
        short8v bv = *(const short8v*)&Wlds[((((size_t)2*16+kt2)*2+nt)*64+lane)*8];
        acc = __builtin_amdgcn_mfma_f32_16x16x32_bf16(av, bv, acc, 0,0,0);
      }
      int colg = g*32 + nt*16 + nl;
      #pragma unroll
      for(int rr=0;rr<4;rr++){
        int brow = q*4+rr;
        pmh[brow*Hh + colg] = acc[rr];
        mS0[brow][nt*16+nl] = acc[rr];
      }
    }
    __syncthreads();

    // ---- phase 6: partial dots B (18) ----
    if(tid<512){
      int b2 = tid>>5, c = tid&31, colg = g*32+c;
      size_t rb = rb16 + (size_t)b2*Hh;
      float mh = mS0[b2][c], mz = mzS[b2][c], hv = hSl[b2][c];
      float xh = XH[rb+colg], xz = XZ[rb+colg];
      float bhc = biasL2[colg], bzc = biasL1[colg];
      float z = sigm(coefA[b2][3]*mz + coefA[b2][4]*xz + coefA[b2][5]*bzc);
      float eh=z*hv, em=z*mh, ex=z*xh, eb=z*bhc;
      float p[18] = {mh*mh, mh*xh, mh*bhc, hv*mh,
                     eh*eh, eh*em, eh*ex, eh*eb,
                     em*em, em*ex, em*eb, ex*ex, ex*eb, eb*eb,
                     hv*eh, hv*em, hv*ex, hv*eb};
      #pragma unroll
      for(int d=0;d<18;d++) p[d] = rsum32f(p[d]);
      if(c==0){
        float* dst = pB + ((size_t)g*16+b2)*18;
        #pragma unroll
        for(int d=0;d<18;d++) dst[d]=p[d];
      }
    }
    gsync();  // sync B

    // ---- phase 7a: sum partials B ----
    if(tid<256){
      int b2 = tid>>4, blk = tid&15;
      const float* src = pB + ((size_t)blk*16+b2)*18;
      float s[18];
      #pragma unroll
      for(int d=0;d<18;d++) s[d]=src[d];
      #pragma unroll
      for(int d=0;d<18;d++) s[d]=rsum16f(s[d]);
      if(blk==0){
        #pragma unroll
        for(int d=0;d<18;d++) dotsB[b2][d]=s[d];
      }
    }
    __syncthreads();

    // ---- phase 7b: update coefficients (16 threads) ----
    if(tid<16){
      int b2 = tid;
      float d0=dotsB[b2][0], d1=dotsB[b2][1], d2=dotsB[b2][2], d3=dotsB[b2][3];
      float Ghh=dotsB[b2][4], Ghm=dotsB[b2][5], Ghx=dotsB[b2][6], Ghb=dotsB[b2][7];
      float Gmm=dotsB[b2][8], Gmx=dotsB[b2][9], Gmb=dotsB[b2][10];
      float Gxx=dotsB[b2][11], Gxb=dotsB[b2][12], Gbb=dotsB[b2][13];
      float Heh=dotsB[b2][14], Hem=dotsB[b2][15], Hex=dotsB[b2][16], Heb=dotsB[b2][17];
      const float* px = pubX + (size_t)(ts*Bb+b2)*6;
      float xhxh=px[4], xhbh=px[5];
      float hxh=dotsA[b2][6], hbh=dotsA[b2][7];
      float bbh=bbT[2]; float Shb=ShT[b2];
      // htil chain
      float nm3=sqrtf(d0+EPSF), se3=tanhf(nm3)/nm3;
      float uvh=se3*d1, uuh=se3*se3*d0, vvh=xhxh;
      float denh=1.f+2.f*uvh+uuh*vvh;
      float a1p=(1.f+2.f*uvh+vvh)*se3/denh, a2p=(1.f-uuh)/denh;
      float uv2h=a1p*d2+a2p*xhbh;
      float uu2h=a1p*a1p*d0+2.f*a1p*a2p*d1+a2p*a2p*xhxh;
      float den2h=1.f+2.f*uv2h+uu2h*bbh;
      float b1p=(1.f+2.f*uv2h+bbh)/den2h, b2p=(1.f-uu2h)/den2h;
      float c1p=b1p*a1p, c2p=b1p*a2p, c3p=b2p;
      float h_htil=c1p*d3+c2p*hxh+c3p*hbh;
      float htil2=c1p*c1p*d0+c2p*c2p*xhxh+c3p*c3p*bbh
                +2.f*(c1p*c2p*d1+c1p*c3p*d2+c2p*c3p*xhbh);
      float denD=1.f-2.f*h_htil+Shb*htil2;
      float dd1=(1.f-2.f*h_htil+htil2)/denD, dd2=(1.f-Shb)/denD;
      float g0=-dd1, g1=dd2*c1p, g2=dd2*c2p, g3=dd2*c3p;
      float del2=g0*g0*Shb+g1*g1*d0+g2*g2*xhxh+g3*g3*bbh
               +2.f*(g0*g1*d3+g0*g2*hxh+g0*g3*hbh+g1*g2*d1+g1*g3*d2+g2*g3*xhbh);
      float ndl=sqrtf(del2+EPSF);
      float sld=atanhf(fminf(ndl,MAXNRM))/ndl;
      float Qe=g0*g0*Ghh+g1*g1*Gmm+g2*g2*Gxx+g3*g3*Gbb
             +2.f*(g0*g1*Ghm+g0*g2*Ghx+g0*g3*Ghb+g1*g2*Gmx+g1*g3*Gmb+g2*g3*Gxb);
      float Le=g0*Heh+g1*Hem+g2*Hex+g3*Heb;
      float Sww=sld*sld*Qe;
      float Shw=sld*Le;
      float nw=sqrtf(Sww+EPSF), sew=tanhf(nw)/nw;
      float uvw=sew*Shw, uuw=Shb, vvw=sew*sew*Sww;
      float denw=1.f+2.f*uvw+uuw*vvw;
      float p1=(1.f+2.f*uvw+vvw)/denw, p2=(1.f-uuw)/denw;
      float q1=p1, q2=p2*sew;
      float n2h=q1*q1*Shb+2.f*q1*q2*Shw+q2*q2*Sww;
      float nrm=sqrtf(n2h+EPSF);
      float scl=fminf(1.f, MAXNRM/nrm);
      float Shn=scl*scl*n2h;
      float nh2=sqrtf(Shn+EPSF);
      float slh=atanhf(fminf(nh2,MAXNRM))/nh2;
      coefB[b2][0]=scl*q1; coefB[b2][1]=scl*q2*sld;
      coefB[b2][2]=g0; coefB[b2][3]=g1; coefB[b2][4]=g2; coefB[b2][5]=g3;
      coefB[b2][6]=slh;
      ShT[b2]=Shn;
    }
    __syncthreads();

    // ---- phase 7c: elementwise h update (all threads, slot (kt=wv, lane)) ----
    {
      int bm = nl;
      int k8 = wv*32 + q*8;
      size_t rb = rb16 + (size_t)bm*Hh;
      f32x4 mh0 = *(const f32x4*)(pmh + bm*Hh + k8);
      f32x4 mh1 = *(const f32x4*)(pmh + bm*Hh + k8 + 4);
      f32x4 mz0 = *(const f32x4*)(pmzW + bm*Hh + k8);
      f32x4 mz1 = *(const f32x4*)(pmzW + bm*Hh + k8 + 4);
      f32x4 xh0 = *(const f32x4*)(XH + rb + k8);
      f32x4 xh1 = *(const f32x4*)(XH + rb + k8 + 4);
      f32x4 xz0 = *(const f32x4*)(XZ + rb + k8);
      f32x4 xz1 = *(const f32x4*)(XZ + rb + k8 + 4);
      float cz1=coefA[bm][3], cz2=coefA[bm][4], cz3=coefA[bm][5];
      float qc1=coefB[bm][0], qc2=coefB[bm][1];
      float g0=coefB[bm][2], g1=coefB[bm][3], g2=coefB[bm][4], g3=coefB[bm][5];
      float slh=coefB[bm][6];
      short8v o;
      #pragma unroll
      for(int i=0;i<4;i++){
        float z = sigm(cz1*mz0[i] + cz2*xz0[i] + cz3*biasL1[k8+i]);
        float dl = g0*hreg[i] + g1*mh0[i] + g2*xh0[i] + g3*biasL2[k8+i];
        float hn = qc1*hreg[i] + qc2*z*dl;
        hreg[i]=hn; lhreg[i]=slh*hn; o[i]=(short)f2bf(lhreg[i]);
      }
      #pragma unroll
      for(int i=0;i<4;i++){
        float z = sigm(cz1*mz1[i] + cz2*xz1[i] + cz3*biasL1[k8+4+i]);
        float dl = g0*hreg[4+i] + g1*mh1[i] + g2*xh1[i] + g3*biasL2[k8+4+i];
        float hn = qc1*hreg[4+i] + qc2*z*dl;
        hreg[4+i]=hn; lhreg[4+i]=slh*hn; o[4+i]=(short)f2bf(lhreg[4+i]);
      }
      *(short8v*)&afAF[((size_t)wv*64+lane)*8] = o;
      if(wv == g){
        f32x4 h0, h1;
        #pragma unroll
        for(int i=0;i<4;i++){ h0[i]=hreg[i]; h1[i]=hreg[4+i]; }
        *(f32x4*)(Xout + rb + k8) = h0;
        *(f32x4*)(Xout + rb + k8 + 4) = h1;
        #pragma unroll
        for(int i=0;i<8;i++) hSl[bm][q*8+i] = hreg[i];
      }
    }
    __syncthreads();
  }
}

// ---------------- fused MLR + online softmax partials ----------------
__global__ __launch_bounds__(256) void k_mlr(const float* __restrict__ X,
    const float* __restrict__ P, const float* __restrict__ A,
    const float* __restrict__ pp, const float* __restrict__ aa, const float* __restrict__ pa,
    const int* __restrict__ tgt, float* __restrict__ pm, float* __restrict__ tl){
  constexpr int RT = 32;
  int split = blockIdx.x;      // 0..7
  int rg = blockIdx.y;         // 0..63
  int rbase = rg*RT;
  __shared__ float Xs[RT][516];
  __shared__ float par[8][RT];
  __shared__ float ms[8][RT][2];
  __shared__ float xxs[RT];
  int tid = threadIdx.x;
  #pragma unroll
  for(int u=0;u<16;u++){
    int fi = u*256 + tid;
    int row = fi >> 7, c4 = fi & 127;
    float4 v = ld4(X + (size_t)(rbase+row)*Hh + c4*4);
    st4(&Xs[row][c4*4], v);
  }
  __syncthreads();
  { int r = tid & 31, seg = tid >> 5;
    float s = 0;
    for(int k=seg*64;k<seg*64+64;k++){ float x = Xs[r][k]; s += x*x; }
    par[seg][r] = s; }
  __syncthreads();
  if(tid < RT){ float s=0; for(int i=0;i<8;i++) s += par[i][tid]; xxs[tid]=s; }
  __syncthreads();
  int r = tid & 31, vi = tid >> 5;
  int rr = rbase + r;
  int tt = rr >> 4, bbr2 = rr & 15;
  int tok = tgt[bbr2*Ss + tt];
  float xx = xxs[r];
  float m = -3.0e38f, sacc = 0.f;
  int v0 = split*1250, v1e = v0 + 1250;
  const float4* Xrow = (const float4*)&Xs[r][0];
  for(int vbv=v0; vbv<v1e; vbv+=8){
    int v = vbv + vi;
    if(v < v1e){
      float px=0, xa=0;
      const float4* Pr = (const float4*)(P + (size_t)v*Hh);
      const float4* Ar = (const float4*)(A + (size_t)v*Hh);
      #pragma unroll 4
      for(int k4=0;k4<128;k4++){
        float4 xv = Xrow[k4];
        float4 pvv = Pr[k4]; float4 av = Ar[k4];
        px += dot4(xv,pvv); xa += dot4(xv,av);
      }
      float ppv = pp[v], aav = aa[v], pav = pa[v];
      float al = 1.f - 2.f*px + xx;
      float be = 1.f - ppv;
      float gm = 1.f - 2.f*px + ppv*xx;
      float da = (-al*pav + be*xa)/gm;
      float dd = (al*al*ppv - 2.f*al*be*px + be*be*xx)/(gm*gm);
      float lam = 2.f/(1.f - ppv);
      float arg = 2.f*da/((1.f - dd)*aav + EPSF);
      float lg = lam*aav*asinhf(arg);
      if(v == tok) tl[rr] = lg;
      if(lg > m){ sacc = sacc*expf(m - lg) + 1.f; m = lg; }
      else sacc += expf(lg - m);
    }
  }
  ms[vi][r][0] = m; ms[vi][r][1] = sacc;
  __syncthreads();
  if(vi==0){
    float M = -3.0e38f;
    for(int i=0;i<8;i++) M = fmaxf(M, ms[i][r][0]);
    float Ssum = 0.f;
    for(int i=0;i<8;i++) Ssum += ms[i][r][1]*expf(ms[i][r][0]-M);
    pm[((size_t)rr*8 + split)*2 + 0] = M;
    pm[((size_t)rr*8 + split)*2 + 1] = Ssum;
  }
}

// ---------------- final merge + mean NLL ----------------
__global__ void k_final(const float* __restrict__ pm, const float* __restrict__ tl, float* __restrict__ out){
  int tid = threadIdx.x;
  __shared__ float sred[4];
  float acc = 0.f;
  for(int q=0;q<8;q++){
    int rr = q*256 + tid;
    float M = -3.0e38f;
    for(int s=0;s<8;s++) M = fmaxf(M, pm[((size_t)rr*8+s)*2]);
    float Ssum = 0.f;
    for(int s=0;s<8;s++) Ssum += pm[((size_t)rr*8+s)*2+1]*expf(pm[((size_t)rr*8+s)*2]-M);
    acc += (M + logf(Ssum)) - tl[rr];
  }
  for(int o=32;o;o>>=1) acc += __shfl_down(acc,o);
  if((tid&63)==0) sred[tid>>6] = acc;
  __syncthreads();
  if(tid==0) out[0] = (sred[0]+sred[1]+sred[2]+sred[3]) / 2048.f;
}

extern "C" void kernel_launch(void* const* d_in, const int* in_sizes, int n_in,
                              void* d_out, int out_size, void* d_ws, size_t ws_size,
                              hipStream_t stream){
  const int* inp = (const int*)d_in[0];
  const int* tgt = (const int*)d_in[1];
  const float* E  = (const float*)d_in[2];
  const float* Wr = (const float*)d_in[3];
  const float* Wz = (const float*)d_in[4];
  const float* Wh = (const float*)d_in[5];
  const float* Ur = (const float*)d_in[6];
  const float* Uz = (const float*)d_in[7];
  const float* Uh = (const float*)d_in[8];
  const float* br = (const float*)d_in[9];
  const float* bz = (const float*)d_in[10];
  const float* bh = (const float*)d_in[11];
  const float* P  = (const float*)d_in[12];
  const float* A  = (const float*)d_in[13];
  float* out = (float*)d_out;
  float* w = (float*)d_ws;
  size_t o = 0;
  auto take = [&](size_t n){ float* p = w + o; o += n; return p; };
  float* Xa  = take((size_t)Nn*Hh);
  float* Xb  = take((size_t)Nn*Hh);
  float* LX  = take((size_t)Nn*Hh);
  float* XR  = take((size_t)Nn*Hh);
  float* XZ  = take((size_t)Nn*Hh);
  float* XH  = take((size_t)Nn*Hh);
  ushort* Wp = (ushort*)take(1179648);       // 3*16*3*16*2*64*8 bf16
  float* pubX = take((size_t)Nn*6);
  float* pmr = take(8192);
  float* pmz = take(16384);                   // double-buffered by step parity
  float* pmh = take(8192);
  float* pA  = take(2048);
  float* pB  = take(4608);
  float* pp  = take(10240);
  float* aa  = take(10240);
  float* pa  = take(10240);
  float* pm  = take((size_t)Nn*8*2);
  float* tl  = take((size_t)Nn);
  int* cnt   = (int*)take(16);
  if(ws_size < o*sizeof(float)) return;

  hipMemsetAsync(cnt, 0, 64, stream);
  hipLaunchKernelGGL(k_pack, dim3(NBLK,9), dim3(1024), 0, stream, Wr,Wz,Wh, Wp);
  hipLaunchKernelGGL(k_pav, dim3(2500), dim3(256), 0, stream, P,A, pp,aa,pa);
  hipLaunchKernelGGL(k_embed, dim3(Nn), dim3(128), 0, stream, inp, E, Xa);
  float* cur = Xa; float* nxt = Xb;
  for(int l=0;l<Ll;l++){
    hipLaunchKernelGGL(k_logmap, dim3(Nn), dim3(128), 0, stream, cur, LX);
    hipLaunchKernelGGL(k_gemm, dim3(24,32), dim3(256), 0, stream, LX,
                       Ur + (size_t)l*Hh*Hh, Uz + (size_t)l*Hh*Hh, Uh + (size_t)l*Hh*Hh,
                       XR, XZ, XH);
    hipLaunchKernelGGL(k_expmap, dim3(Nn,3), dim3(128), 0, stream, XR,XZ,XH);
    hipLaunchKernelGGL(k_predots, dim3(Nn), dim3(128), 0, stream, XR,XZ,XH,
                       br + l*Hh, bz + l*Hh, bh + l*Hh, pubX);
    hipLaunchKernelGGL(k_scan3, dim3(NBLK), dim3(1024), 0, stream, XR,XZ,XH,
                       Wp + (size_t)l*NBLK*49152,
                       br + l*Hh, bz + l*Hh, bh + l*Hh,
                       pubX, pmr, pmz, pmh, pA, pB, cnt + l, nxt);
    float* tmp = cur; cur = nxt; nxt = tmp;
  }
  hipLaunchKernelGGL(k_mlr, dim3(8,64), dim3(256), 0, stream, cur, P, A, pp,aa,pa, tgt, pm, tl);
  hipLaunchKernelGGL(k_final, dim3(1), dim3(256), 0, stream, pm, tl, out);
}

// Round 4
// 12413.734 us; speedup vs baseline: 1.4096x; 1.4096x over previous
//
#include <hip/hip_runtime.h>
#include <hip/hip_bf16.h>
#include <math.h>

#define EPSF 1e-7f
#define MAXNRM 0.99999f

static constexpr int Bb = 16, Ss = 128, Hh = 512, Vv = 10000, Ll = 3;
static constexpr int Nn = Bb * Ss; // 2048
static constexpr int NBLK = 16;    // scan blocks (hidden-dim split)

typedef __attribute__((ext_vector_type(8))) short short8v;
typedef __attribute__((ext_vector_type(4))) float f32x4;

__device__ inline float4 ld4(const float* p){ return *(const float4*)p; }
__device__ inline void st4(float* p, float4 v){ *(float4*)p = v; }
__device__ inline float dot4(float4 a, float4 b){ return a.x*b.x + a.y*b.y + a.z*b.z + a.w*b.w; }
__device__ inline float sigm(float x){ return 1.f/(1.f + expf(-x)); }
__device__ inline unsigned short f2bf(float f){
  __hip_bfloat16 h = __float2bfloat16(f);
  return __builtin_bit_cast(unsigned short, h);
}
__device__ inline float rsum64f(float v){
  v+=__shfl_xor(v,32); v+=__shfl_xor(v,16); v+=__shfl_xor(v,8);
  v+=__shfl_xor(v,4);  v+=__shfl_xor(v,2);  v+=__shfl_xor(v,1); return v;
}
__device__ inline float rsum32f(float v){
  v+=__shfl_xor(v,16); v+=__shfl_xor(v,8); v+=__shfl_xor(v,4);
  v+=__shfl_xor(v,2);  v+=__shfl_xor(v,1); return v;
}
__device__ inline float rsum16f(float v){
  v+=__shfl_xor(v,8); v+=__shfl_xor(v,4); v+=__shfl_xor(v,2); v+=__shfl_xor(v,1); return v;
}

// ---- coherent (LLC point-of-coherence) memory ops: bypass local L1/L2 via sc0 sc1 ----
__device__ inline void stg_sc(float* p, float v){
  asm volatile("global_store_dword %0, %1, off sc0 sc1" :: "v"(p), "v"(v) : "memory");
}
// 8 consecutive floats from one base
__device__ inline void ldg_sc8(const float* p, f32x4& a, f32x4& b){
  asm volatile(
    "global_load_dwordx4 %0, %2, off sc0 sc1\n\t"
    "global_load_dwordx4 %1, %2, off offset:16 sc0 sc1\n\t"
    "s_waitcnt vmcnt(0)"
    : "=&v"(a), "=&v"(b) : "v"(p) : "memory");
}
// 8 floats from each of two bases
__device__ inline void ldg_sc8x2(const float* p0, const float* p1,
                                 f32x4& a, f32x4& b, f32x4& c, f32x4& d){
  asm volatile(
    "global_load_dwordx4 %0, %4, off sc0 sc1\n\t"
    "global_load_dwordx4 %1, %4, off offset:16 sc0 sc1\n\t"
    "global_load_dwordx4 %2, %5, off sc0 sc1\n\t"
    "global_load_dwordx4 %3, %5, off offset:16 sc0 sc1\n\t"
    "s_waitcnt vmcnt(0)"
    : "=&v"(a), "=&v"(b), "=&v"(c), "=&v"(d) : "v"(p0), "v"(p1) : "memory");
}
// 20 consecutive floats from one base
__device__ inline void ldg_sc20(const float* p, f32x4& a, f32x4& b, f32x4& c, f32x4& d, f32x4& e){
  asm volatile(
    "global_load_dwordx4 %0, %5, off sc0 sc1\n\t"
    "global_load_dwordx4 %1, %5, off offset:16 sc0 sc1\n\t"
    "global_load_dwordx4 %2, %5, off offset:32 sc0 sc1\n\t"
    "global_load_dwordx4 %3, %5, off offset:48 sc0 sc1\n\t"
    "global_load_dwordx4 %4, %5, off offset:64 sc0 sc1\n\t"
    "s_waitcnt vmcnt(0)"
    : "=&v"(a), "=&v"(b), "=&v"(c), "=&v"(d), "=&v"(e) : "v"(p) : "memory");
}

// ---------------- pack W[l][j][k] -> bf16 MFMA B-fragments per scan-block ----------------
__global__ void k_pack(const float* __restrict__ Wr, const float* __restrict__ Wz,
                       const float* __restrict__ Wh, ushort* __restrict__ Wp){
  int g = blockIdx.x, lm = blockIdx.y;
  int l = lm/3, mat = lm%3;
  const float* W = (mat==0?Wr:mat==1?Wz:Wh) + (size_t)l*Hh*Hh;
  int tid = threadIdx.x;
  int kt = tid>>6, lane = tid&63, q = (lane>>4)&3, nl = lane&15;
  #pragma unroll
  for(int nt=0;nt<2;nt++){
    int j = g*32 + nt*16 + nl;
    int k0 = kt*32 + q*8;
    const float* src = W + (size_t)j*Hh + k0;
    union { ushort u[8]; uint4 v; } tmp;
    #pragma unroll
    for(int i=0;i<8;i++) tmp.u[i] = f2bf(src[i]);
    size_t off = ((((((size_t)l*NBLK + g)*3 + mat)*16 + kt)*2 + nt)*64 + lane)*8;
    *(uint4*)(Wp + off) = tmp.v;
  }
}

// ---------------- per-(t,b) input-only dots ----------------
__global__ void k_predots(const float* __restrict__ XR, const float* __restrict__ XZ,
                          const float* __restrict__ XH,
                          const float* __restrict__ br, const float* __restrict__ bz,
                          const float* __restrict__ bh, float* __restrict__ pubX){
  int n = blockIdx.x; int tid = threadIdx.x; // 128 threads
  float s0=0,s1=0,s2=0,s3=0,s4=0,s5=0;
  for(int i=tid;i<Hh;i+=128){
    float xr=XR[(size_t)n*Hh+i], xz=XZ[(size_t)n*Hh+i], xh=XH[(size_t)n*Hh+i];
    s0+=xr*xr; s1+=xr*br[i]; s2+=xz*xz; s3+=xz*bz[i]; s4+=xh*xh; s5+=xh*bh[i];
  }
  __shared__ float red[2][6];
  s0=rsum64f(s0); s1=rsum64f(s1); s2=rsum64f(s2);
  s3=rsum64f(s3); s4=rsum64f(s4); s5=rsum64f(s5);
  int w = tid>>6;
  if((tid&63)==0){ red[w][0]=s0; red[w][1]=s1; red[w][2]=s2; red[w][3]=s3; red[w][4]=s4; red[w][5]=s5; }
  __syncthreads();
  if(tid==0){
    #pragma unroll
    for(int d=0;d<6;d++) pubX[(size_t)n*6+d] = red[0][d]+red[1][d];
  }
}

// ---------------- per-vocab constants ----------------
__global__ void k_pav(const float* __restrict__ P, const float* __restrict__ A,
                      float* __restrict__ pp, float* __restrict__ aa, float* __restrict__ pa){
  int w = threadIdx.x >> 6, lane = threadIdx.x & 63;
  int v = blockIdx.x*4 + w;
  const float4* Pr = (const float4*)(P + (size_t)v*Hh);
  const float4* Ar = (const float4*)(A + (size_t)v*Hh);
  float sp=0, sa=0, spa=0;
  #pragma unroll
  for(int i=0;i<2;i++){
    int k4 = lane*2 + i;
    float4 pv = Pr[k4], av = Ar[k4];
    sp += dot4(pv,pv); sa += dot4(av,av); spa += dot4(pv,av);
  }
  for(int o=32;o;o>>=1){ sp+=__shfl_down(sp,o); sa+=__shfl_down(sa,o); spa+=__shfl_down(spa,o); }
  if(lane==0){ pp[v]=sp; aa[v]=sqrtf(sa+EPSF); pa[v]=spa; }
}

// ---------------- embedding gather ----------------
__global__ void k_embed(const int* __restrict__ inp, const float* __restrict__ E, float* __restrict__ X){
  int n = blockIdx.x; int t = n >> 4, b = n & 15;
  int tok = inp[b*Ss + t];
  int i = threadIdx.x;
  st4(X + (size_t)n*Hh + i*4, ld4(E + (size_t)tok*Hh + i*4));
}

// ---------------- row logmap0 ----------------
__global__ void k_logmap(const float* __restrict__ X, float* __restrict__ LX){
  int n = blockIdx.x; int t = threadIdx.x;
  __shared__ float sred[2];
  float4 v = ld4(X + (size_t)n*Hh + t*4);
  float ss = dot4(v,v);
  for(int o=32;o;o>>=1) ss += __shfl_down(ss,o);
  if((t&63)==0) sred[t>>6] = ss;
  __syncthreads();
  ss = sred[0]+sred[1];
  float nn = sqrtf(ss + EPSF);
  float sc = atanhf(fminf(nn, MAXNRM)) / nn;
  v.x*=sc; v.y*=sc; v.z*=sc; v.w*=sc;
  st4(LX + (size_t)n*Hh + t*4, v);
}

// ---------------- row expmap0 (in place, 3 buffers) ----------------
__global__ void k_expmap(float* __restrict__ XR, float* __restrict__ XZ, float* __restrict__ XH){
  float* Xp = blockIdx.y==0 ? XR : (blockIdx.y==1 ? XZ : XH);
  int n = blockIdx.x; int t = threadIdx.x;
  __shared__ float sred[2];
  float4 v = ld4(Xp + (size_t)n*Hh + t*4);
  float ss = dot4(v,v);
  for(int o=32;o;o>>=1) ss += __shfl_down(ss,o);
  if((t&63)==0) sred[t>>6] = ss;
  __syncthreads();
  ss = sred[0]+sred[1];
  float nn = sqrtf(ss + EPSF);
  float sc = tanhf(nn) / nn;
  v.x*=sc; v.y*=sc; v.z*=sc; v.w*=sc;
  st4(Xp + (size_t)n*Hh + t*4, v);
}

// ---------------- GEMM: LX[2048,512] @ {Ur|Uz|Uh}^T ----------------
__global__ __launch_bounds__(256) void k_gemm(const float* __restrict__ A4,
    const float* __restrict__ U0, const float* __restrict__ U1, const float* __restrict__ U2,
    float* __restrict__ O0, float* __restrict__ O1, float* __restrict__ O2){
  __shared__ float As[16][65], Bs[16][65];
  int jb = blockIdx.x;
  int nb = blockIdx.y;
  int mat = jb >> 3; int j0 = (jb & 7)*64;
  const float* Bm = mat==0?U0 : (mat==1?U1:U2);
  float* Om       = mat==0?O0 : (mat==1?O1:O2);
  int tid = threadIdx.x;
  int lr = tid >> 2, lq = tid & 3;
  int tx = tid & 15, ty = tid >> 4;
  float acc[4][4] = {};
  for(int kb=0; kb<Hh; kb+=16){
    float4 av = ld4(A4 + (size_t)(nb*64+lr)*Hh + kb + lq*4);
    float4 bv = ld4(Bm + (size_t)(j0+lr)*Hh + kb + lq*4);
    As[lq*4+0][lr]=av.x; As[lq*4+1][lr]=av.y; As[lq*4+2][lr]=av.z; As[lq*4+3][lr]=av.w;
    Bs[lq*4+0][lr]=bv.x; Bs[lq*4+1][lr]=bv.y; Bs[lq*4+2][lr]=bv.z; Bs[lq*4+3][lr]=bv.w;
    __syncthreads();
    #pragma unroll
    for(int kk=0;kk<16;kk++){
      float a0=As[kk][ty*4+0], a1=As[kk][ty*4+1], a2=As[kk][ty*4+2], a3=As[kk][ty*4+3];
      float b0=Bs[kk][tx*4+0], b1=Bs[kk][tx*4+1], b2=Bs[kk][tx*4+2], b3=Bs[kk][tx*4+3];
      acc[0][0]+=a0*b0; acc[0][1]+=a0*b1; acc[0][2]+=a0*b2; acc[0][3]+=a0*b3;
      acc[1][0]+=a1*b0; acc[1][1]+=a1*b1; acc[1][2]+=a1*b2; acc[1][3]+=a1*b3;
      acc[2][0]+=a2*b0; acc[2][1]+=a2*b1; acc[2][2]+=a2*b2; acc[2][3]+=a2*b3;
      acc[3][0]+=a3*b0; acc[3][1]+=a3*b1; acc[3][2]+=a3*b2; acc[3][3]+=a3*b3;
    }
    __syncthreads();
  }
  for(int i=0;i<4;i++)
    for(int j2=0;j2<4;j2++)
      Om[(size_t)(nb*64+ty*4+i)*Hh + j0 + tx*4 + j2] = acc[i][j2];
}

// ---------------- cooperative hidden-split GRU scan, LLC-coherent exchange ----------------
// 16 blocks x 1024 threads. Block g owns hidden cols [g*32, g*32+32).
// Weights LDS-resident. 2 counter-barrier syncs per step; NO threadfence/L2 flush.
__global__ __launch_bounds__(1024) void k_scan4(
    const float* __restrict__ XR, const float* __restrict__ XZ, const float* __restrict__ XH,
    const ushort* __restrict__ Wp_l,
    const float* __restrict__ br, const float* __restrict__ bz, const float* __restrict__ bh,
    const float* __restrict__ pubX,
    float* __restrict__ Emr, float* __restrict__ Emz, float* __restrict__ Emh,
    float* __restrict__ pA, float* __restrict__ pB,
    int* __restrict__ cnt, float* __restrict__ Xout){
  const int g = blockIdx.x;
  const int tid = threadIdx.x;
  const int lane = tid & 63, wv = tid >> 6;  // 16 waves
  const int q = (lane>>4)&3, nl = lane&15;

  __shared__ ushort Wlds[3*16*2*64*8];   // 96 KB
  __shared__ ushort afAF[16*64*8];       // 16 KB A-frag (lh, then ap)
  __shared__ float biasL0[Hh], biasL1[Hh], biasL2[Hh];
  __shared__ float mS0[16][32];
  __shared__ float mzS[16][32];
  __shared__ float hSl[16][32];
  __shared__ float dotsA[16][8];
  __shared__ float dotsB[16][18];
  __shared__ float coefA[16][8];
  __shared__ float coefB[16][8];
  __shared__ float ShT[16];
  __shared__ float bbT[4];

  {
    const uint4* srcW = (const uint4*)(Wp_l + (size_t)g*49152);
    uint4* dstW = (uint4*)Wlds;
    #pragma unroll
    for(int i=0;i<6;i++) dstW[i*1024+tid] = srcW[i*1024+tid];
  }
  for(int i=tid;i<Hh;i+=1024){ biasL0[i]=br[i]; biasL1[i]=bz[i]; biasL2[i]=bh[i]; }
  { uint4 z4 = {0,0,0,0}; ((uint4*)afAF)[tid] = z4; }
  if(tid<512) hSl[tid>>5][tid&31] = 0.f;
  if(tid<16) ShT[tid] = 0.f;
  __syncthreads();
  // bias grams (block-local, redundant across blocks)
  {
    float p0=0,p1=0,p2=0;
    if(tid<512){ float a=biasL0[tid],b2=biasL1[tid],c2=biasL2[tid]; p0=a*a; p1=b2*b2; p2=c2*c2; }
    p0=rsum64f(p0); p1=rsum64f(p1); p2=rsum64f(p2);
    if(tid<512 && (tid&63)==0){ dotsB[tid>>6][0]=p0; dotsB[tid>>6][1]=p1; dotsB[tid>>6][2]=p2; }
    __syncthreads();
    if(tid==0){
      float a=0,b2=0,c2=0;
      for(int i=0;i<8;i++){ a+=dotsB[i][0]; b2+=dotsB[i][1]; c2+=dotsB[i][2]; }
      bbT[0]=a; bbT[1]=b2; bbT[2]=c2;
    }
    __syncthreads();
  }

  float hreg[8], lhreg[8];
  #pragma unroll
  for(int i=0;i<8;i++){ hreg[i]=0.f; lhreg[i]=0.f; }

  // one-shot counter barrier: drain own stores, add, spin. No cache maintenance.
  auto gsync = [&](int idx){
    asm volatile("s_waitcnt vmcnt(0) lgkmcnt(0)" ::: "memory");
    __syncthreads();
    if(tid==0){
      __hip_atomic_fetch_add(cnt+idx, 1, __ATOMIC_RELAXED, __HIP_MEMORY_SCOPE_AGENT);
      while(__hip_atomic_load(cnt+idx, __ATOMIC_RELAXED, __HIP_MEMORY_SCOPE_AGENT) < NBLK)
        __builtin_amdgcn_s_sleep(2);
    }
    __syncthreads();
  };

  for(int ts=0; ts<Ss; ts++){
    const size_t rb16 = (size_t)(ts*Bb)*Hh;
    const int par = ts & 1;
    float* EmrP = Emr + par*8192;
    float* EmzP = Emz + par*8192;
    float* EmhP = Emh + par*8192;
    float* pA_  = pA  + par*2048;
    float* pB_  = pB  + par*5120;

    // ---- P2: matvec r/z via MFMA (waves 0..3) ----
    if(wv < 4){
      int mat = wv>>1, nt = wv&1;
      f32x4 acc = {0.f,0.f,0.f,0.f};
      #pragma unroll
      for(int kt2=0;kt2<16;kt2++){
        short8v av = *(const short8v*)&afAF[((size_t)kt2*64+lane)*8];
        short8v bv = *(const short8v*)&Wlds[((((size_t)mat*16+kt2)*2+nt)*64+lane)*8];
        acc = __builtin_amdgcn_mfma_f32_16x16x32_bf16(av, bv, acc, 0,0,0);
      }
      float* pdst = (mat==0)? EmrP : EmzP;
      int colg = g*32 + nt*16 + nl;
      #pragma unroll
      for(int rr=0;rr<4;rr++){
        int brow = q*4+rr;
        stg_sc(pdst + brow*Hh + colg, acc[rr]);
        if(mat==0) mS0[brow][nt*16+nl] = acc[rr];
        else       mzS[brow][nt*16+nl] = acc[rr];
      }
    }
    __syncthreads();

    // ---- P3: partial A-dots over own slice ----
    if(tid<512){
      int b2 = tid>>5, c = tid&31, colg = g*32+c;
      size_t rb = rb16 + (size_t)b2*Hh;
      float mr = mS0[b2][c], mz = mzS[b2][c], hv = hSl[b2][c];
      float xr = XR[rb+colg], xz = XZ[rb+colg], xh = XH[rb+colg];
      float brc = biasL0[colg], bzc = biasL1[colg], bhc = biasL2[colg];
      float p[8] = {mr*mr, mr*xr, mr*brc, mz*mz, mz*xz, mz*bzc, hv*xh, hv*bhc};
      #pragma unroll
      for(int d=0;d<8;d++) p[d] = rsum32f(p[d]);
      if(c==0){
        float* dst = pA_ + ((size_t)g*16+b2)*8;
        #pragma unroll
        for(int d=0;d<8;d++) stg_sc(dst+d, p[d]);
      }
    }
    gsync(2*ts);  // ---- sync A ----

    // ---- P4a: sum pA partials (sc-loads) ----
    if(tid<256){
      int b2 = tid>>4, blk = tid&15;
      f32x4 s0,s1;
      ldg_sc8(pA_ + ((size_t)blk*16+b2)*8, s0, s1);
      float s[8] = {s0[0],s0[1],s0[2],s0[3],s1[0],s1[1],s1[2],s1[3]};
      #pragma unroll
      for(int d=0;d<8;d++) s[d]=rsum16f(s[d]);
      if(blk==0){
        #pragma unroll
        for(int d=0;d<8;d++) dotsA[b2][d]=s[d];
      }
    }
    __syncthreads();

    // ---- P4b: gate coefficients (16 threads) ----
    if(tid<16){
      int b2 = tid;
      float s0=dotsA[b2][0], s1=dotsA[b2][1], s2=dotsA[b2][2];
      float s3=dotsA[b2][3], s4=dotsA[b2][4], s5=dotsA[b2][5];
      const float* px = pubX + (size_t)(ts*Bb+b2)*6;
      float xrxr=px[0], xrbr=px[1], xzxz=px[2], xzbz=px[3];
      float bbr=bbT[0], bbz=bbT[1];
      float nm=sqrtf(s0+EPSF), se=tanhf(nm)/nm;
      float uv=se*s1, uu=se*se*s0, vvr=xrxr;
      float den=1.f+2.f*uv+uu*vvr;
      float a1=(1.f+2.f*uv+vvr)*se/den, a2=(1.f-uu)/den;
      float uv2=a1*s2+a2*xrbr;
      float uu2=a1*a1*s0+2.f*a1*a2*s1+a2*a2*xrxr;
      float den2=1.f+2.f*uv2+uu2*bbr;
      float b1=(1.f+2.f*uv2+bbr)/den2, b2c=(1.f-uu2)/den2;
      float c1=b1*a1, c2=b1*a2, c3=b2c;
      float n2sq=c1*c1*s0+c2*c2*xrxr+c3*c3*bbr+2.f*(c1*c2*s1+c1*c3*s2+c2*c3*xrbr);
      float nn2=sqrtf(n2sq+EPSF);
      float s_r=atanhf(fminf(nn2,MAXNRM))/nn2;
      coefA[b2][0]=s_r*c1; coefA[b2][1]=s_r*c2; coefA[b2][2]=s_r*c3;
      float nmz=sqrtf(s3+EPSF), sez=tanhf(nmz)/nmz;
      float uvz=sez*s4, uuz=sez*sez*s3, vvz=xzxz;
      float denz=1.f+2.f*uvz+uuz*vvz;
      float az1=(1.f+2.f*uvz+vvz)*sez/denz, az2=(1.f-uuz)/denz;
      float uvz2=az1*s5+az2*xzbz;
      float uuz2=az1*az1*s3+2.f*az1*az2*s4+az2*az2*xzxz;
      float denz2=1.f+2.f*uvz2+uuz2*bbz;
      float bz1=(1.f+2.f*uvz2+bbz)/denz2, bz2=(1.f-uuz2)/denz2;
      float cz1=bz1*az1, cz2=bz1*az2, cz3=bz2;
      float nz2sq=cz1*cz1*s3+cz2*cz2*xzxz+cz3*cz3*bbz+2.f*(cz1*cz2*s4+cz1*cz3*s5+cz2*cz3*xzbz);
      float nnz2=sqrtf(nz2sq+EPSF);
      float s_z=atanhf(fminf(nnz2,MAXNRM))/nnz2;
      coefA[b2][3]=s_z*cz1; coefA[b2][4]=s_z*cz2; coefA[b2][5]=s_z*cz3;
    }
    __syncthreads();

    // ---- P4c: build ap A-fragment (all threads; needs full mr via sc-load) ----
    {
      int bm = nl;
      int k8 = wv*32 + q*8;
      size_t rb = rb16 + (size_t)bm*Hh;
      f32x4 m0, m1;
      ldg_sc8(EmrP + bm*Hh + k8, m0, m1);
      f32x4 x0 = *(const f32x4*)(XR + rb + k8);
      f32x4 x1 = *(const f32x4*)(XR + rb + k8 + 4);
      float ca=coefA[bm][0], cb=coefA[bm][1], cc=coefA[bm][2];
      short8v o;
      #pragma unroll
      for(int i=0;i<4;i++){
        float rr1 = sigm(ca*m0[i] + cb*x0[i] + cc*biasL0[k8+i]);
        o[i] = (short)f2bf(rr1*lhreg[i]);
      }
      #pragma unroll
      for(int i=0;i<4;i++){
        float rr1 = sigm(ca*m1[i] + cb*x1[i] + cc*biasL0[k8+4+i]);
        o[4+i] = (short)f2bf(rr1*lhreg[4+i]);
      }
      *(short8v*)&afAF[((size_t)wv*64+lane)*8] = o;
    }
    __syncthreads();

    // ---- P5: matvec h via MFMA (waves 0..1) ----
    if(wv < 2){
      int nt = wv;
      f32x4 acc = {0.f,0.f,0.f,0.f};
      #pragma unroll
      for(int kt2=0;kt2<16;kt2++){
        short8v av = *(const short8v*)&afAF[((size_t)kt2*64+lane)*8];
        short8v bv = *(const short8v*)&Wlds[((((size_t)2*16+kt2)*2+nt)*64+lane)*8];
        acc = __builtin_amdgcn_mfma_f32_16x16x32_bf16(av, bv, acc, 0,0,0);
      }
      int colg = g*32 + nt*16 + nl;
      #pragma unroll
      for(int rr=0;rr<4;rr++){
        int brow = q*4+rr;
        stg_sc(EmhP + brow*Hh + colg, acc[rr]);
        mS0[brow][nt*16+nl] = acc[rr];
      }
    }
    __syncthreads();

    // ---- P6: partial B-dots (18) over own slice ----
    if(tid<512){
      int b2 = tid>>5, c = tid&31, colg = g*32+c;
      size_t rb = rb16 + (size_t)b2*Hh;
      float mh = mS0[b2][c], mz = mzS[b2][c], hv = hSl[b2][c];
      float xh = XH[rb+colg], xz = XZ[rb+colg];
      float bhc = biasL2[colg], bzc = biasL1[colg];
      float z = sigm(coefA[b2][3]*mz + coefA[b2][4]*xz + coefA[b2][5]*bzc);
      float eh=z*hv, em=z*mh, ex=z*xh, eb=z*bhc;
      float p[18] = {mh*mh, mh*xh, mh*bhc, hv*mh,
                     eh*eh, eh*em, eh*ex, eh*eb,
                     em*em, em*ex, em*eb, ex*ex, ex*eb, eb*eb,
                     hv*eh, hv*em, hv*ex, hv*eb};
      #pragma unroll
      for(int d=0;d<18;d++) p[d] = rsum32f(p[d]);
      if(c==0){
        float* dst = pB_ + ((size_t)g*16+b2)*20;
        #pragma unroll
        for(int d=0;d<18;d++) stg_sc(dst+d, p[d]);
      }
    }
    gsync(2*ts+1);  // ---- sync B ----

    // ---- P7a: sum pB partials (sc-loads) ----
    if(tid<256){
      int b2 = tid>>4, blk = tid&15;
      f32x4 a,b,c,d,e;
      ldg_sc20(pB_ + ((size_t)blk*16+b2)*20, a,b,c,d,e);
      float s[18] = {a[0],a[1],a[2],a[3], b[0],b[1],b[2],b[3],
                     c[0],c[1],c[2],c[3], d[0],d[1],d[2],d[3], e[0],e[1]};
      #pragma unroll
      for(int d2=0;d2<18;d2++) s[d2]=rsum16f(s[d2]);
      if(blk==0){
        #pragma unroll
        for(int d2=0;d2<18;d2++) dotsB[b2][d2]=s[d2];
      }
    }
    __syncthreads();

    // ---- P7b: update coefficients (16 threads) ----
    if(tid<16){
      int b2 = tid;
      float d0=dotsB[b2][0], d1=dotsB[b2][1], d2=dotsB[b2][2], d3=dotsB[b2][3];
      float Ghh=dotsB[b2][4], Ghm=dotsB[b2][5], Ghx=dotsB[b2][6], Ghb=dotsB[b2][7];
      float Gmm=dotsB[b2][8], Gmx=dotsB[b2][9], Gmb=dotsB[b2][10];
      float Gxx=dotsB[b2][11], Gxb=dotsB[b2][12], Gbb=dotsB[b2][13];
      float Heh=dotsB[b2][14], Hem=dotsB[b2][15], Hex=dotsB[b2][16], Heb=dotsB[b2][17];
      const float* px = pubX + (size_t)(ts*Bb+b2)*6;
      float xhxh=px[4], xhbh=px[5];
      float hxh=dotsA[b2][6], hbh=dotsA[b2][7];
      float bbh=bbT[2]; float Shb=ShT[b2];
      float nm3=sqrtf(d0+EPSF), se3=tanhf(nm3)/nm3;
      float uvh=se3*d1, uuh=se3*se3*d0, vvh=xhxh;
      float denh=1.f+2.f*uvh+uuh*vvh;
      float a1p=(1.f+2.f*uvh+vvh)*se3/denh, a2p=(1.f-uuh)/denh;
      float uv2h=a1p*d2+a2p*xhbh;
      float uu2h=a1p*a1p*d0+2.f*a1p*a2p*d1+a2p*a2p*xhxh;
      float den2h=1.f+2.f*uv2h+uu2h*bbh;
      float b1p=(1.f+2.f*uv2h+bbh)/den2h, b2p=(1.f-uu2h)/den2h;
      float c1p=b1p*a1p, c2p=b1p*a2p, c3p=b2p;
      float h_htil=c1p*d3+c2p*hxh+c3p*hbh;
      float htil2=c1p*c1p*d0+c2p*c2p*xhxh+c3p*c3p*bbh
                +2.f*(c1p*c2p*d1+c1p*c3p*d2+c2p*c3p*xhbh);
      float denD=1.f-2.f*h_htil+Shb*htil2;
      float dd1=(1.f-2.f*h_htil+htil2)/denD, dd2=(1.f-Shb)/denD;
      float g0=-dd1, g1=dd2*c1p, g2=dd2*c2p, g3=dd2*c3p;
      float del2=g0*g0*Shb+g1*g1*d0+g2*g2*xhxh+g3*g3*bbh
               +2.f*(g0*g1*d3+g0*g2*hxh+g0*g3*hbh+g1*g2*d1+g1*g3*d2+g2*g3*xhbh);
      float ndl=sqrtf(del2+EPSF);
      float sld=atanhf(fminf(ndl,MAXNRM))/ndl;
      float Qe=g0*g0*Ghh+g1*g1*Gmm+g2*g2*Gxx+g3*g3*Gbb
             +2.f*(g0*g1*Ghm+g0*g2*Ghx+g0*g3*Ghb+g1*g2*Gmx+g1*g3*Gmb+g2*g3*Gxb);
      float Le=g0*Heh+g1*Hem+g2*Hex+g3*Heb;
      float Sww=sld*sld*Qe;
      float Shw=sld*Le;
      float nw=sqrtf(Sww+EPSF), sew=tanhf(nw)/nw;
      float uvw=sew*Shw, uuw=Shb, vvw=sew*sew*Sww;
      float denw=1.f+2.f*uvw+uuw*vvw;
      float p1=(1.f+2.f*uvw+vvw)/denw, p2=(1.f-uuw)/denw;
      float q1=p1, q2=p2*sew;
      float n2h=q1*q1*Shb+2.f*q1*q2*Shw+q2*q2*Sww;
      float nrm=sqrtf(n2h+EPSF);
      float scl=fminf(1.f, MAXNRM/nrm);
      float Shn=scl*scl*n2h;
      float nh2=sqrtf(Shn+EPSF);
      float slh=atanhf(fminf(nh2,MAXNRM))/nh2;
      coefB[b2][0]=scl*q1; coefB[b2][1]=scl*q2*sld;
      coefB[b2][2]=g0; coefB[b2][3]=g1; coefB[b2][4]=g2; coefB[b2][5]=g3;
      coefB[b2][6]=slh;
      ShT[b2]=Shn;
    }
    __syncthreads();

    // ---- P9: redundant full h update (all threads; sc-load mh,mz) ----
    {
      int bm = nl;
      int k8 = wv*32 + q*8;
      size_t rb = rb16 + (size_t)bm*Hh;
      f32x4 mh0,mh1,mz0,mz1;
      ldg_sc8x2(EmhP + bm*Hh + k8, EmzP + bm*Hh + k8, mh0,mh1,mz0,mz1);
      f32x4 xh0 = *(const f32x4*)(XH + rb + k8);
      f32x4 xh1 = *(const f32x4*)(XH + rb + k8 + 4);
      f32x4 xz0 = *(const f32x4*)(XZ + rb + k8);
      f32x4 xz1 = *(const f32x4*)(XZ + rb + k8 + 4);
      float cz1=coefA[bm][3], cz2=coefA[bm][4], cz3=coefA[bm][5];
      float qc1=coefB[bm][0], qc2=coefB[bm][1];
      float g0=coefB[bm][2], g1=coefB[bm][3], g2=coefB[bm][4], g3=coefB[bm][5];
      float slh=coefB[bm][6];
      short8v o;
      #pragma unroll
      for(int i=0;i<4;i++){
        float z = sigm(cz1*mz0[i] + cz2*xz0[i] + cz3*biasL1[k8+i]);
        float dl = g0*hreg[i] + g1*mh0[i] + g2*xh0[i] + g3*biasL2[k8+i];
        float hn = qc1*hreg[i] + qc2*z*dl;
        hreg[i]=hn; lhreg[i]=slh*hn; o[i]=(short)f2bf(lhreg[i]);
      }
      #pragma unroll
      for(int i=0;i<4;i++){
        float z = sigm(cz1*mz1[i] + cz2*xz1[i] + cz3*biasL1[k8+4+i]);
        float dl = g0*hreg[4+i] + g1*mh1[i] + g2*xh1[i] + g3*biasL2[k8+4+i];
        float hn = qc1*hreg[4+i] + qc2*z*dl;
        hreg[4+i]=hn; lhreg[4+i]=slh*hn; o[4+i]=(short)f2bf(lhreg[4+i]);
      }
      *(short8v*)&afAF[((size_t)wv*64+lane)*8] = o;
      if(wv == g){
        f32x4 h0, h1;
        #pragma unroll
        for(int i=0;i<4;i++){ h0[i]=hreg[i]; h1[i]=hreg[4+i]; }
        *(f32x4*)(Xout + rb + k8) = h0;
        *(f32x4*)(Xout + rb + k8 + 4) = h1;
        #pragma unroll
        for(int i=0;i<8;i++) hSl[bm][q*8+i] = hreg[i];
      }
    }
    __syncthreads();
  }
}

// ---------------- fused MLR + online softmax partials ----------------
__global__ __launch_bounds__(256) void k_mlr(const float* __restrict__ X,
    const float* __restrict__ P, const float* __restrict__ A,
    const float* __restrict__ pp, const float* __restrict__ aa, const float* __restrict__ pa,
    const int* __restrict__ tgt, float* __restrict__ pm, float* __restrict__ tl){
  constexpr int RT = 32;
  int split = blockIdx.x;      // 0..7
  int rg = blockIdx.y;         // 0..63
  int rbase = rg*RT;
  __shared__ float Xs[RT][516];
  __shared__ float par[8][RT];
  __shared__ float ms[8][RT][2];
  __shared__ float xxs[RT];
  int tid = threadIdx.x;
  #pragma unroll
  for(int u=0;u<16;u++){
    int fi = u*256 + tid;
    int row = fi >> 7, c4 = fi & 127;
    float4 v = ld4(X + (size_t)(rbase+row)*Hh + c4*4);
    st4(&Xs[row][c4*4], v);
  }
  __syncthreads();
  { int r = tid & 31, seg = tid >> 5;
    float s = 0;
    for(int k=seg*64;k<seg*64+64;k++){ float x = Xs[r][k]; s += x*x; }
    par[seg][r] = s; }
  __syncthreads();
  if(tid < RT){ float s=0; for(int i=0;i<8;i++) s += par[i][tid]; xxs[tid]=s; }
  __syncthreads();
  int r = tid & 31, vi = tid >> 5;
  int rr = rbase + r;
  int tt = rr >> 4, bbr2 = rr & 15;
  int tok = tgt[bbr2*Ss + tt];
  float xx = xxs[r];
  float m = -3.0e38f, sacc = 0.f;
  int v0 = split*1250, v1e = v0 + 1250;
  const float4* Xrow = (const float4*)&Xs[r][0];
  for(int vbv=v0; vbv<v1e; vbv+=8){
    int v = vbv + vi;
    if(v < v1e){
      float px=0, xa=0;
      const float4* Pr = (const float4*)(P + (size_t)v*Hh);
      const float4* Ar = (const float4*)(A + (size_t)v*Hh);
      #pragma unroll 4
      for(int k4=0;k4<128;k4++){
        float4 xv = Xrow[k4];
        float4 pvv = Pr[k4]; float4 av = Ar[k4];
        px += dot4(xv,pvv); xa += dot4(xv,av);
      }
      float ppv = pp[v], aav = aa[v], pav = pa[v];
      float al = 1.f - 2.f*px + xx;
      float be = 1.f - ppv;
      float gm = 1.f - 2.f*px + ppv*xx;
      float da = (-al*pav + be*xa)/gm;
      float dd = (al*al*ppv - 2.f*al*be*px + be*be*xx)/(gm*gm);
      float lam = 2.f/(1.f - ppv);
      float arg = 2.f*da/((1.f - dd)*aav + EPSF);
      float lg = lam*aav*asinhf(arg);
      if(v == tok) tl[rr] = lg;
      if(lg > m){ sacc = sacc*expf(m - lg) + 1.f; m = lg; }
      else sacc += expf(lg - m);
    }
  }
  ms[vi][r][0] = m; ms[vi][r][1] = sacc;
  __syncthreads();
  if(vi==0){
    float M = -3.0e38f;
    for(int i=0;i<8;i++) M = fmaxf(M, ms[i][r][0]);
    float Ssum = 0.f;
    for(int i=0;i<8;i++) Ssum += ms[i][r][1]*expf(ms[i][r][0]-M);
    pm[((size_t)rr*8 + split)*2 + 0] = M;
    pm[((size_t)rr*8 + split)*2 + 1] = Ssum;
  }
}

// ---------------- final merge + mean NLL ----------------
__global__ void k_final(const float* __restrict__ pm, const float* __restrict__ tl, float* __restrict__ out){
  int tid = threadIdx.x;
  __shared__ float sred[4];
  float acc = 0.f;
  for(int q=0;q<8;q++){
    int rr = q*256 + tid;
    float M = -3.0e38f;
    for(int s=0;s<8;s++) M = fmaxf(M, pm[((size_t)rr*8+s)*2]);
    float Ssum = 0.f;
    for(int s=0;s<8;s++) Ssum += pm[((size_t)rr*8+s)*2+1]*expf(pm[((size_t)rr*8+s)*2]-M);
    acc += (M + logf(Ssum)) - tl[rr];
  }
  for(int o=32;o;o>>=1) acc += __shfl_down(acc,o);
  if((tid&63)==0) sred[tid>>6] = acc;
  __syncthreads();
  if(tid==0) out[0] = (sred[0]+sred[1]+sred[2]+sred[3]) / 2048.f;
}

extern "C" void kernel_launch(void* const* d_in, const int* in_sizes, int n_in,
                              void* d_out, int out_size, void* d_ws, size_t ws_size,
                              hipStream_t stream){
  const int* inp = (const int*)d_in[0];
  const int* tgt = (const int*)d_in[1];
  const float* E  = (const float*)d_in[2];
  const float* Wr = (const float*)d_in[3];
  const float* Wz = (const float*)d_in[4];
  const float* Wh = (const float*)d_in[5];
  const float* Ur = (const float*)d_in[6];
  const float* Uz = (const float*)d_in[7];
  const float* Uh = (const float*)d_in[8];
  const float* br = (const float*)d_in[9];
  const float* bz = (const float*)d_in[10];
  const float* bh = (const float*)d_in[11];
  const float* P  = (const float*)d_in[12];
  const float* A  = (const float*)d_in[13];
  float* out = (float*)d_out;
  float* w = (float*)d_ws;
  size_t o = 0;
  auto take = [&](size_t n){ float* p = w + o; o += n; return p; };
  float* Xa  = take((size_t)Nn*Hh);
  float* Xb  = take((size_t)Nn*Hh);
  float* LX  = take((size_t)Nn*Hh);
  float* XR  = take((size_t)Nn*Hh);
  float* XZ  = take((size_t)Nn*Hh);
  float* XH  = take((size_t)Nn*Hh);
  ushort* Wp = (ushort*)take(1179648);
  float* pubX = take((size_t)Nn*6);
  float* Emr = take(2*8192);
  float* Emz = take(2*8192);
  float* Emh = take(2*8192);
  float* pA  = take(2*2048);
  float* pB  = take(2*5120);
  float* pp  = take(10240);
  float* aa  = take(10240);
  float* pa  = take(10240);
  float* pm  = take((size_t)Nn*8*2);
  float* tl  = take((size_t)Nn);
  int* cnt   = (int*)take(Ll*Ss*2);
  if(ws_size < o*sizeof(float)) return;

  hipMemsetAsync(cnt, 0, Ll*Ss*2*sizeof(int), stream);
  hipLaunchKernelGGL(k_pack, dim3(NBLK,9), dim3(1024), 0, stream, Wr,Wz,Wh, Wp);
  hipLaunchKernelGGL(k_pav, dim3(2500), dim3(256), 0, stream, P,A, pp,aa,pa);
  hipLaunchKernelGGL(k_embed, dim3(Nn), dim3(128), 0, stream, inp, E, Xa);
  float* cur = Xa; float* nxt = Xb;
  for(int l=0;l<Ll;l++){
    hipLaunchKernelGGL(k_logmap, dim3(Nn), dim3(128), 0, stream, cur, LX);
    hipLaunchKernelGGL(k_gemm, dim3(24,32), dim3(256), 0, stream, LX,
                       Ur + (size_t)l*Hh*Hh, Uz + (size_t)l*Hh*Hh, Uh + (size_t)l*Hh*Hh,
                       XR, XZ, XH);
    hipLaunchKernelGGL(k_expmap, dim3(Nn,3), dim3(128), 0, stream, XR,XZ,XH);
    hipLaunchKernelGGL(k_predots, dim3(Nn), dim3(128), 0, stream, XR,XZ,XH,
                       br + l*Hh, bz + l*Hh, bh + l*Hh, pubX);
    hipLaunchKernelGGL(k_scan4, dim3(NBLK), dim3(1024), 0, stream, XR,XZ,XH,
                       Wp + (size_t)l*NBLK*49152,
                       br + l*Hh, bz + l*Hh, bh + l*Hh,
                       pubX, Emr, Emz, Emh, pA, pB, cnt + l*Ss*2, nxt);
    float* tmp = cur; cur = nxt; nxt = tmp;
  }
  hipLaunchKernelGGL(k_mlr, dim3(8,64), dim3(256), 0, stream, cur, P, A, pp,aa,pa, tgt, pm, tl);
  hipLaunchKernelGGL(k_final, dim3(1), dim3(256), 0, stream, pm, tl, out);
}